// Round 2
// baseline (12451.587 us; speedup 1.0000x reference)
//
#include <hip/hip_runtime.h>
#include <stdint.h>

// Problem constants
#define BB   128      // batch
#define DD   512      // input dim
#define HH   1024     // hidden dim
#define SS   512      // seq len
#define G4   4096     // 4*H gate rows
#define KK_TOT 48     // (D+H)/32 k-steps
#define NT_TOT 256    // G4/16 n-tiles
#define NT_FC  64
#define KK_FC  32

#define USTRIDE 264   // fc kernel LDS stride (round-1 path, unchanged)
#define UST     136   // persistent kernel staging stride in shorts (272 B = 17 x 16B slots)
#define NCHUNK  12    // K=1536 in chunks of 128
#define WPC     64    // WGs per chain (barrier group)

typedef __attribute__((ext_vector_type(8))) short short8v;
typedef __attribute__((ext_vector_type(4))) float float4v;

__device__ __forceinline__ unsigned short f2bf(float f) {
    union { float f; unsigned int u; } v; v.f = f;
    unsigned int u = v.u;
    unsigned int r = u + 0x7FFFu + ((u >> 16) & 1u);   // RNE
    return (unsigned short)(r >> 16);
}
__device__ __forceinline__ float sigm(float z) { return 1.f / (1.f + __expf(-z)); }
__device__ __forceinline__ float tanh_f(float z) { float e = __expf(2.f * z); return 1.f - 2.f / (e + 1.f); }

__device__ __forceinline__ void cvt16(const float4 f0, const float4 f1,
                                      const float4 f2, const float4 f3,
                                      short8v& o0, short8v& o1) {
    o0[0]=(short)f2bf(f0.x); o0[1]=(short)f2bf(f0.y); o0[2]=(short)f2bf(f0.z); o0[3]=(short)f2bf(f0.w);
    o0[4]=(short)f2bf(f1.x); o0[5]=(short)f2bf(f1.y); o0[6]=(short)f2bf(f1.z); o0[7]=(short)f2bf(f1.w);
    o1[0]=(short)f2bf(f2.x); o1[1]=(short)f2bf(f2.y); o1[2]=(short)f2bf(f2.z); o1[3]=(short)f2bf(f2.w);
    o1[4]=(short)f2bf(f3.x); o1[5]=(short)f2bf(f3.y); o1[6]=(short)f2bf(f3.z); o1[7]=(short)f2bf(f3.w);
}

// ---------------------------------------------------------------------------
// Pack W = [W_ih | W_hh] rows permuted to r = 4*j + q into bf16 MFMA fragment
// order: wp[((ntile*48 + kk)*64 + lane)*8 + i] = W[ntile*16+(lane&15)][kk*32+(lane>>4)*8+i]
// ---------------------------------------------------------------------------
__global__ void pack_w_kernel(const float* __restrict__ W_ih,
                              const float* __restrict__ W_hh,
                              unsigned short* __restrict__ wp) {
    int idx = blockIdx.x * 256 + threadIdx.x;
    if (idx >= NT_TOT * KK_TOT * 64) return;
    int lane  = idx & 63;
    int kk    = (idx >> 6) % KK_TOT;
    int ntile = idx / (64 * KK_TOT);
    int r = ntile * 16 + (lane & 15);
    int j = r >> 2, q = r & 3;
    int orow = q * HH + j;
    int kbase = kk * 32 + (lane >> 4) * 8;
    short8v ov;
#pragma unroll
    for (int i = 0; i < 8; ++i) {
        int k = kbase + i;
        float v = (k < DD) ? W_ih[(size_t)orow * DD + k]
                           : W_hh[(size_t)orow * HH + (k - DD)];
        ov[i] = (short)f2bf(v);
    }
    *(short8v*)&wp[(size_t)idx * 8] = ov;
}

__global__ void pack_fc_kernel(const float* __restrict__ fc_w,
                               unsigned short* __restrict__ wfc) {
    int idx = blockIdx.x * 256 + threadIdx.x;
    if (idx >= NT_FC * KK_FC * 64) return;
    int lane  = idx & 63;
    int kk    = (idx >> 6) % KK_FC;
    int ntile = idx / (64 * KK_FC);
    int o = ntile * 16 + (lane & 15);
    int kbase = kk * 32 + (lane >> 4) * 8;
    short8v ov;
#pragma unroll
    for (int i = 0; i < 8; ++i)
        ov[i] = (short)f2bf(fc_w[(size_t)o * HH + kbase + i]);
    *(short8v*)&wfc[(size_t)idx * 8] = ov;
}

__global__ void init_kernel(const float* __restrict__ b_ih,
                            const float* __restrict__ b_hh,
                            unsigned short* __restrict__ h0,
                            float* __restrict__ bpp,
                            unsigned int* __restrict__ bar) {
    int i = blockIdx.x * 256 + threadIdx.x;
    if (i < BB * HH) h0[i] = 0;
    if (i < G4) { int j = i >> 2, q = i & 3; bpp[i] = b_ih[q * HH + j] + b_hh[q * HH + j]; }
    if (i < 1024) bar[i] = 0;
}

// ---------------------------------------------------------------------------
// Persistent LSTM: 256 WGs = 4 chains (32 batch rows each) x 64 WGs.
// Each WG: gate tile M=32 x N=64 packed rows; W_hh slice resident in LDS,
// W_ih slice resident in VGPRs; c-state in VGPRs; one 64-WG barrier per step.
// ---------------------------------------------------------------------------
__launch_bounds__(256, 1)
__global__ void lstm_persist(const float* __restrict__ x,
                             const unsigned short* __restrict__ wp,
                             const float* __restrict__ bp,
                             unsigned short* __restrict__ hbuf0,
                             unsigned short* __restrict__ hbuf1,
                             unsigned int* __restrict__ bar) {
    __shared__ __align__(16) unsigned short walds[4 * 32 * 64 * 8]; // 128 KiB W_hh frags
    __shared__ __align__(16) unsigned short ustage[32 * UST];       // 8704 B staging / gates

    const int tid = threadIdx.x;
    const int bid = blockIdx.x;
    const int chain = (bid & 7) >> 1;            // 0..3 (2 XCD-slots per chain if bid%8=xcd)
    const int ng   = (bid >> 3) * 2 + (bid & 1); // 0..63 within chain
    const int lane = tid & 63;
    const int w    = tid >> 6;                   // wave 0..3 (N split)
    const int l15  = lane & 15;
    const int lhi  = lane >> 4;

    // W_ih fragments (kk 0..15) for this wave's ntile -> VGPRs (64 VGPR/lane)
    const size_t ntile = (size_t)(ng * 4 + w);
    short8v wih[16];
#pragma unroll
    for (int kk = 0; kk < 16; ++kk)
        wih[kk] = *(const short8v*)&wp[((ntile * KK_TOT + kk) * 64 + lane) * 8];

    // W_hh fragments (kk 16..47) for the WG's 4 ntiles -> LDS
    for (int i = 0; i < 32; ++i) {
        int idx = tid + 256 * i;                 // 8192 fragments of 16 B
        int sl = idx & 63, kh = (idx >> 6) & 31, ntl = idx >> 11;
        short8v v = *(const short8v*)&wp[(((size_t)(ng * 4 + ntl) * KK_TOT + 16 + kh) * 64 + sl) * 8];
        *(short8v*)&walds[(size_t)((ntl * 32 + kh) * 64 + sl) * 8] = v;
    }

    // epilogue constants: thread owns cells (em, ejl) and (em+16, ejl)
    const int em  = tid >> 4;                    // 0..15
    const int ejl = tid & 15;
    const float4 bias = *(const float4*)&bp[(ng * 16 + ejl) * 4];
    float c0 = 0.f, c1 = 0.f;

    const int srow = tid >> 3;                   // staging row 0..31
    const int scol = (tid & 7) * 16;             // staging col (shorts)
    const size_t xrow_base = (size_t)(chain * 32 + srow) * SS * DD;
    const size_t hrow_off  = (size_t)(chain * 32 + srow) * HH + scol;

    unsigned int* cnt = bar + chain * 32;
    unsigned int* gen = bar + 512 + chain * 32;

    float* glds = (float*)ustage;                // gates alias (32 x 68 fp32 = 8704 B)

    __syncthreads();                             // walds ready

#pragma unroll 1
    for (int t = 0; t < SS; ++t) {
        const unsigned short* hin = (t & 1) ? hbuf1 : hbuf0;
        unsigned short* hout      = (t & 1) ? hbuf0 : hbuf1;

        float4v acc0 = {0.f, 0.f, 0.f, 0.f};
        float4v acc1 = {0.f, 0.f, 0.f, 0.f};

        // prologue: load+convert+write chunk 0 (x region)
        short8v s0, s1;
        {
            const float* xp = &x[xrow_base + (size_t)t * DD + scol];
            cvt16(*(const float4*)(xp + 0), *(const float4*)(xp + 4),
                  *(const float4*)(xp + 8), *(const float4*)(xp + 12), s0, s1);
        }
        *(short8v*)&ustage[srow * UST + scol]     = s0;
        *(short8v*)&ustage[srow * UST + scol + 8] = s1;

#pragma unroll
        for (int c = 0; c < NCHUNK; ++c) {
            __syncthreads();                     // chunk c staged for all
            if (c < NCHUNK - 1) {                // issue next chunk's loads early
                if (c + 1 < 4) {
                    const float* xp = &x[xrow_base + (size_t)t * DD + (c + 1) * 128 + scol];
                    cvt16(*(const float4*)(xp + 0), *(const float4*)(xp + 4),
                          *(const float4*)(xp + 8), *(const float4*)(xp + 12), s0, s1);
                } else {
                    const unsigned short* hp = &hin[hrow_off + (size_t)(c + 1 - 4) * 128];
                    s0 = *(const short8v*)(hp);
                    s1 = *(const short8v*)(hp + 8);
                }
            }
#pragma unroll
            for (int kl = 0; kl < 4; ++kl) {     // MFMA on chunk c
                const int kkg = c * 4 + kl;
                short8v a0 = *(const short8v*)&ustage[l15 * UST + kl * 32 + lhi * 8];
                short8v a1 = *(const short8v*)&ustage[(l15 + 16) * UST + kl * 32 + lhi * 8];
                short8v b;
                if (kkg < 16) b = wih[kkg];
                else          b = *(const short8v*)&walds[(size_t)((w * 32 + (kkg - 16)) * 64 + lane) * 8];
                acc0 = __builtin_amdgcn_mfma_f32_16x16x32_bf16(a0, b, acc0, 0, 0, 0);
                acc1 = __builtin_amdgcn_mfma_f32_16x16x32_bf16(a1, b, acc1, 0, 0, 0);
            }
            __syncthreads();                     // all waves done reading chunk c
            if (c < NCHUNK - 1) {
                *(short8v*)&ustage[srow * UST + scol]     = s0;
                *(short8v*)&ustage[srow * UST + scol + 8] = s1;
            }
        }

        // ---- epilogue: gates -> LDS (alias), fused activation + state ----
#pragma unroll
        for (int r = 0; r < 4; ++r) {
            glds[(lhi * 4 + r) * 68 + w * 16 + l15]        = acc0[r];
            glds[(16 + lhi * 4 + r) * 68 + w * 16 + l15]   = acc1[r];
        }
        __syncthreads();
        float4 g0 = *(const float4*)&glds[em * 68 + ejl * 4];
        float4 g1 = *(const float4*)&glds[(em + 16) * 68 + ejl * 4];
        {
            float ig = sigm(g0.x + bias.x), fg = sigm(g0.y + bias.y);
            float gg = tanh_f(g0.z + bias.z), og = sigm(g0.w + bias.w);
            c0 = fg * c0 + ig * gg;
            hout[(size_t)(chain * 32 + em) * HH + ng * 16 + ejl] = f2bf(og * tanh_f(c0));
        }
        {
            float ig = sigm(g1.x + bias.x), fg = sigm(g1.y + bias.y);
            float gg = tanh_f(g1.z + bias.z), og = sigm(g1.w + bias.w);
            c1 = fg * c1 + ig * gg;
            hout[(size_t)(chain * 32 + em + 16) * HH + ng * 16 + ejl] = f2bf(og * tanh_f(c1));
        }
        __syncthreads();                          // glds reads + h stores drained

        // ---- chain barrier (64 WGs, sense-reversing, device scope) ----
        if (tid == 0) {
            __threadfence();                      // release: flush to device scope
            unsigned int g = __hip_atomic_load(gen, __ATOMIC_RELAXED, __HIP_MEMORY_SCOPE_AGENT);
            unsigned int a = __hip_atomic_fetch_add(cnt, 1u, __ATOMIC_ACQ_REL, __HIP_MEMORY_SCOPE_AGENT);
            if (a == WPC - 1) {
                __hip_atomic_store(cnt, 0u, __ATOMIC_RELAXED, __HIP_MEMORY_SCOPE_AGENT);
                __hip_atomic_fetch_add(gen, 1u, __ATOMIC_RELEASE, __HIP_MEMORY_SCOPE_AGENT);
            } else {
                while (__hip_atomic_load(gen, __ATOMIC_RELAXED, __HIP_MEMORY_SCOPE_AGENT) == g)
                    __builtin_amdgcn_s_sleep(2);
            }
            __threadfence();                      // acquire: invalidate for fresh h reads
        }
        __syncthreads();
    }
}

// ---------------------------------------------------------------------------
// out[128,1024] = h_fin @ fc_w^T + fc_b  (fp32 out). 32 WGs: 2 Mg x 16 Ng.
// ---------------------------------------------------------------------------
__launch_bounds__(256)
__global__ void fc_kernel(const unsigned short* __restrict__ hfin,
                          const unsigned short* __restrict__ wfc,
                          const float* __restrict__ fc_b,
                          float* __restrict__ out) {
    __shared__ __align__(16) char smem[64 * USTRIDE * 2];
    unsigned short* ulds = (unsigned short*)smem;
    const int tid = threadIdx.x, bid = blockIdx.x;
    const int mg = bid >> 4;
    const int ng = bid & 15;
    const int m0 = mg * 64;
    const int lane = tid & 63, wave = tid >> 6;
    const int wm = wave >> 1, wn = wave & 1;

    float4v acc[2][2] = {};
    for (int c = 0; c < 4; ++c) {
        __syncthreads();
        for (int it = 0; it < 16; ++it) {
            int v = tid + 256 * it;
            int row = v >> 6;
            int kl = (v & 63) * 4;
            ushort4 hv = *(const ushort4*)&hfin[(size_t)(m0 + row) * HH + c * 256 + kl];
            *(ushort4*)&ulds[row * USTRIDE + kl] = hv;
        }
        __syncthreads();
#pragma unroll
        for (int kk = 0; kk < 8; ++kk) {
            int kkg = c * 8 + kk;
            short8v a[2], b[2];
#pragma unroll
            for (int mt = 0; mt < 2; ++mt) {
                int row = wm * 32 + mt * 16 + (lane & 15);
                a[mt] = *(const short8v*)&ulds[row * USTRIDE + kk * 32 + (lane >> 4) * 8];
            }
#pragma unroll
            for (int nt = 0; nt < 2; ++nt) {
                int ntile = ng * 4 + wn * 2 + nt;
                b[nt] = *(const short8v*)&wfc[(((size_t)ntile * KK_FC + kkg) * 64 + lane) * 8];
            }
#pragma unroll
            for (int mt = 0; mt < 2; ++mt)
#pragma unroll
                for (int nt = 0; nt < 2; ++nt)
                    acc[mt][nt] = __builtin_amdgcn_mfma_f32_16x16x32_bf16(
                        a[mt], b[nt], acc[mt][nt], 0, 0, 0);
        }
    }
#pragma unroll
    for (int mt = 0; mt < 2; ++mt)
#pragma unroll
        for (int nt = 0; nt < 2; ++nt)
#pragma unroll
            for (int r = 0; r < 4; ++r) {
                int mrow = m0 + wm * 32 + mt * 16 + (lane >> 4) * 4 + r;
                int o = ng * 64 + wn * 32 + nt * 16 + (lane & 15);
                out[(size_t)mrow * HH + o] = acc[mt][nt][r] + fc_b[o];
            }
}

// ---------------------------------------------------------------------------
extern "C" void kernel_launch(void* const* d_in, const int* in_sizes, int n_in,
                              void* d_out, int out_size, void* d_ws, size_t ws_size,
                              hipStream_t stream) {
    const float* x    = (const float*)d_in[0];
    const float* W_ih = (const float*)d_in[1];
    const float* W_hh = (const float*)d_in[2];
    const float* b_ih = (const float*)d_in[3];
    const float* b_hh = (const float*)d_in[4];
    const float* fc_w = (const float*)d_in[5];
    const float* fc_b = (const float*)d_in[6];
    float* out = (float*)d_out;

    char* ws = (char*)d_ws;
    size_t off = 0;
    unsigned short* wp  = (unsigned short*)(ws + off); off += (size_t)NT_TOT * KK_TOT * 64 * 8 * 2; // 12 MB
    unsigned short* wfc = (unsigned short*)(ws + off); off += (size_t)NT_FC * KK_FC * 64 * 8 * 2;   // 2 MB
    float* bp  = (float*)(ws + off); off += (size_t)G4 * 4;
    unsigned short* hbuf0 = (unsigned short*)(ws + off); off += (size_t)BB * HH * 2;
    unsigned short* hbuf1 = (unsigned short*)(ws + off); off += (size_t)BB * HH * 2;
    unsigned int* bar = (unsigned int*)(ws + off); off += 4096;
    if (ws_size < off) return;

    pack_w_kernel<<<3072, 256, 0, stream>>>(W_ih, W_hh, wp);
    pack_fc_kernel<<<512, 256, 0, stream>>>(fc_w, wfc);
    init_kernel<<<512, 256, 0, stream>>>(b_ih, b_hh, hbuf0, bp, bar);

    lstm_persist<<<256, 256, 0, stream>>>(x, wp, bp, hbuf0, hbuf1, bar);

    // S=512 even -> final h in hbuf0
    fc_kernel<<<32, 256, 0, stream>>>(hbuf0, wfc, fc_b, out);
}

// Round 4
// 12360.667 us; speedup vs baseline: 1.0074x; 1.0074x over previous
//
#include <hip/hip_runtime.h>
#include <stdint.h>

// Problem constants
#define BB   128
#define DD   512
#define HH   1024
#define SS   512
#define G4   4096
#define KKT  48       // (D+H)/32 k-steps
#define KRES 28       // kk 0..27 resident in VGPRs
#define KSTR 20       // kk 28..47 streamed each step
#define NT_FC 64
#define KK_FC 32
#define USTRIDE 264   // fc kernel LDS stride

typedef __attribute__((ext_vector_type(8))) short short8v;
typedef __attribute__((ext_vector_type(4))) float float4v;

__device__ __forceinline__ unsigned short f2bf(float f) {
    union { float f; unsigned int u; } v; v.f = f;
    unsigned int u = v.u;
    unsigned int r = u + 0x7FFFu + ((u >> 16) & 1u);   // RNE
    return (unsigned short)(r >> 16);
}
__device__ __forceinline__ float sigm(float z) { return 1.f / (1.f + __expf(-z)); }
__device__ __forceinline__ float tanh_f(float z) { float e = __expf(2.f * z); return 1.f - 2.f / (e + 1.f); }

__device__ __forceinline__ short8v cvt8(const float4 f0, const float4 f1) {
    short8v o;
    o[0]=(short)f2bf(f0.x); o[1]=(short)f2bf(f0.y); o[2]=(short)f2bf(f0.z); o[3]=(short)f2bf(f0.w);
    o[4]=(short)f2bf(f1.x); o[5]=(short)f2bf(f1.y); o[6]=(short)f2bf(f1.z); o[7]=(short)f2bf(f1.w);
    return o;
}

// ---------------------------------------------------------------------------
// Pack W = [W_ih | W_hh] into bf16 MFMA fragment order, q-major n-tiles:
// ntile = q*64 + jg  ->  W row = q*H + jg*16 + (lane&15), k = kk*32+(lane>>4)*8
// wp[((ntile*48 + kk)*64 + lane)*8 + i]
// ---------------------------------------------------------------------------
__global__ void pack_w_kernel(const float* __restrict__ W_ih,
                              const float* __restrict__ W_hh,
                              unsigned short* __restrict__ wp) {
    int idx = blockIdx.x * 256 + threadIdx.x;
    if (idx >= 256 * KKT * 64) return;
    int lane  = idx & 63;
    int kk    = (idx >> 6) % KKT;
    int ntile = idx / (64 * KKT);
    int q = ntile >> 6;
    int orow = q * HH + (ntile & 63) * 16 + (lane & 15);
    int kbase = kk * 32 + (lane >> 4) * 8;
    short8v ov;
#pragma unroll
    for (int i = 0; i < 8; ++i) {
        int k = kbase + i;
        float v = (k < DD) ? W_ih[(size_t)orow * DD + k]
                           : W_hh[(size_t)orow * HH + (k - DD)];
        ov[i] = (short)f2bf(v);
    }
    *(short8v*)&wp[(size_t)idx * 8] = ov;
}

__global__ void pack_fc_kernel(const float* __restrict__ fc_w,
                               unsigned short* __restrict__ wfc) {
    int idx = blockIdx.x * 256 + threadIdx.x;
    if (idx >= NT_FC * KK_FC * 64) return;
    int lane  = idx & 63;
    int kk    = (idx >> 6) % KK_FC;
    int ntile = idx / (64 * KK_FC);
    int o = ntile * 16 + (lane & 15);
    int kbase = kk * 32 + (lane >> 4) * 8;
    short8v ov;
#pragma unroll
    for (int i = 0; i < 8; ++i)
        ov[i] = (short)f2bf(fc_w[(size_t)o * HH + kbase + i]);
    *(short8v*)&wfc[(size_t)idx * 8] = ov;
}

// x -> bf16 MFMA A-fragment order: xpre[((mtile*S + t)*16 + kk)*64 + lane]
// holds x[b = mtile*16 + (lane&15)][t][kk*32 + (lane>>4)*8 + i]
__global__ void pack_x_kernel(const float* __restrict__ x,
                              unsigned short* __restrict__ xpre) {
    int idx = blockIdx.x * 256 + threadIdx.x;
    if (idx >= 8 * SS * 16 * 64) return;
    int lane  = idx & 63;
    int kk    = (idx >> 6) & 15;
    int t     = (idx >> 10) & (SS - 1);
    int mtile = idx >> 19;
    int b = mtile * 16 + (lane & 15);
    int d = kk * 32 + (lane >> 4) * 8;
    const float* src = &x[((size_t)b * SS + t) * DD + d];
    short8v ov;
#pragma unroll
    for (int i = 0; i < 8; ++i) ov[i] = (short)f2bf(src[i]);
    *(short8v*)&xpre[(size_t)idx * 8] = ov;
}

// zero h0 + barrier state, pack bias bp[j*4+q] = b_ih[q*H+j] + b_hh[q*H+j]
__global__ void init_kernel(const float* __restrict__ b_ih,
                            const float* __restrict__ b_hh,
                            unsigned short* __restrict__ h0,
                            float* __restrict__ bpp,
                            unsigned int* __restrict__ bar) {
    int i = blockIdx.x * 256 + threadIdx.x;
    if (i < BB * HH) h0[i] = 0;
    if (i < G4) { int j = i >> 2, q = i & 3; bpp[i] = b_ih[q * HH + j] + b_hh[q * HH + j]; }
    if (i < 2048) bar[i] = 0;
}

// ---------------------------------------------------------------------------
// Persistent LSTM: 128 WGs = 2 chains (64 batch rows) x 64 WGs (16 j each).
// Wave tile: 2 m-tiles x 2 q-tiles x 16 j, 192 MFMAs/step.
// W: 28 kk VGPR-resident + 20 kk streamed. h staged in LDS frag-major.
// Tree barrier (8 same-XCD groups of 8); x-projection overlaps barrier wait.
// ---------------------------------------------------------------------------
template<int PRE>
__launch_bounds__(256, 1)
__global__ void lstm_persist(const float* __restrict__ x,
                             const unsigned short* __restrict__ xpre,
                             const unsigned short* __restrict__ wp,
                             const float* __restrict__ bp,
                             unsigned short* __restrict__ hbuf0,
                             unsigned short* __restrict__ hbuf1,
                             unsigned int* __restrict__ bar) {
    __shared__ __align__(16) unsigned short hl[4 * 32 * 64 * 8];  // 128 KiB h frags [mt][kkh][lane]
    __shared__ __align__(16) float gl[64 * 68 + 4];               // 17.4 KiB gate exchange

    const int tid = threadIdx.x;
    const int bid = blockIdx.x;
    const int c   = (bid >> 3) & 1;                 // chain 0..1
    const int jg  = (bid & 7) | ((bid >> 4) << 3);  // 0..63 (same jg across chains -> same XCD)
    const int grp = bid & 7;                        // barrier local group (XCD class)
    const int lane = tid & 63;
    const int w    = tid >> 6;
    const int mtp  = w >> 1;                        // m-tile pair 0..1
    const int qp   = w & 1;                         // q pair 0..1
    const int l15  = lane & 15;
    const int lhi  = lane >> 4;

    unsigned int* lcnt = bar + c * 1024 + grp * 32;
    unsigned int* lgen = bar + c * 1024 + 256 + grp * 32;
    unsigned int* gcnt = bar + c * 1024 + 512;
    unsigned int* ggen = bar + c * 1024 + 544;

    // ---- resident W (kk 0..27), 224 VGPRs ----
    short8v wres[2][KRES];
#pragma unroll
    for (int qi = 0; qi < 2; ++qi) {
        const size_t qt = (size_t)((qp * 2 + qi) * 64 + jg);
#pragma unroll
        for (int kk = 0; kk < KRES; ++kk)
            wres[qi][kk] = *(const short8v*)&wp[((qt * KKT + kk) * 64 + lane) * 8];
    }

    // ---- epilogue constants: thread owns 4 cells (row erow, j = ej0..ej0+3) ----
    const int erow = tid >> 2;                      // 0..63
    const int ej0  = (tid & 3) * 4;
    float4 eb[4];
#pragma unroll
    for (int jj = 0; jj < 4; ++jj)
        eb[jj] = *(const float4*)&bp[(jg * 16 + ej0 + jj) * 4];
    float ec0 = 0.f, ec1 = 0.f, ec2 = 0.f, ec3 = 0.f;

    const int srow = tid >> 2;                      // stage row 0..63
    const int sseg = tid & 3;                       // stage segment (256 cols each)

#pragma unroll 1
    for (int t = 0; t < SS; ++t) {
        const unsigned short* hin = (t & 1) ? hbuf1 : hbuf0;
        unsigned short* hout      = (t & 1) ? hbuf0 : hbuf1;

        __syncthreads();                            // S2: prior step fully done

        // ---- barrier arrive (tree) ----
        bool leader = false;
        if (tid == 0) {
            __threadfence();
            unsigned int a = __hip_atomic_fetch_add(lcnt, 1u, __ATOMIC_ACQ_REL, __HIP_MEMORY_SCOPE_AGENT);
            if (a == 7u) {
                leader = true;
                unsigned int b = __hip_atomic_fetch_add(gcnt, 1u, __ATOMIC_ACQ_REL, __HIP_MEMORY_SCOPE_AGENT);
                if (b == 7u) {
                    __hip_atomic_store(gcnt, 0u, __ATOMIC_RELAXED, __HIP_MEMORY_SCOPE_AGENT);
                    __hip_atomic_fetch_add(ggen, 1u, __ATOMIC_RELEASE, __HIP_MEMORY_SCOPE_AGENT);
                }
            }
        }

        float4v acc[2][2] = {};

        // ---- x-phase (kk 0..15) — independent of h, overlaps barrier ----
#pragma unroll
        for (int kk = 0; kk < 16; ++kk) {
            short8v a0, a1;
            if (PRE) {
                a0 = *(const short8v*)&xpre[(((size_t)((c*4 + mtp*2 + 0) * SS + t) * 16 + kk) * 64 + lane) * 8];
                a1 = *(const short8v*)&xpre[(((size_t)((c*4 + mtp*2 + 1) * SS + t) * 16 + kk) * 64 + lane) * 8];
            } else {
                const float* p0 = &x[((size_t)((c*4 + mtp*2 + 0) * 16 + l15) * SS + t) * DD + kk*32 + lhi*8];
                const float* p1 = &x[((size_t)((c*4 + mtp*2 + 1) * 16 + l15) * SS + t) * DD + kk*32 + lhi*8];
                a0 = cvt8(*(const float4*)p0, *(const float4*)(p0 + 4));
                a1 = cvt8(*(const float4*)p1, *(const float4*)(p1 + 4));
            }
            acc[0][0] = __builtin_amdgcn_mfma_f32_16x16x32_bf16(a0, wres[0][kk], acc[0][0], 0,0,0);
            acc[0][1] = __builtin_amdgcn_mfma_f32_16x16x32_bf16(a0, wres[1][kk], acc[0][1], 0,0,0);
            acc[1][0] = __builtin_amdgcn_mfma_f32_16x16x32_bf16(a1, wres[0][kk], acc[1][0], 0,0,0);
            acc[1][1] = __builtin_amdgcn_mfma_f32_16x16x32_bf16(a1, wres[1][kk], acc[1][1], 0,0,0);
        }

        // ---- barrier wait ----
        if (tid == 0) {
            const unsigned int target = (unsigned int)(t + 1);
            if (leader) {
                while (__hip_atomic_load(ggen, __ATOMIC_ACQUIRE, __HIP_MEMORY_SCOPE_AGENT) < target)
                    __builtin_amdgcn_s_sleep(1);
                __hip_atomic_store(lcnt, 0u, __ATOMIC_RELAXED, __HIP_MEMORY_SCOPE_AGENT);
                __hip_atomic_store(lgen, target, __ATOMIC_RELEASE, __HIP_MEMORY_SCOPE_AGENT);
            } else {
                while (__hip_atomic_load(lgen, __ATOMIC_ACQUIRE, __HIP_MEMORY_SCOPE_AGENT) < target)
                    __builtin_amdgcn_s_sleep(1);
            }
            __threadfence();
        }
        __syncthreads();                            // S3: h(t-1) visible everywhere

        // ---- streamed W (kk 28..47) ----
        short8v wst[2][KSTR];
#pragma unroll
        for (int qi = 0; qi < 2; ++qi) {
            const size_t qt = (size_t)((qp * 2 + qi) * 64 + jg);
#pragma unroll
            for (int kk = 0; kk < KSTR; ++kk)
                wst[qi][kk] = *(const short8v*)&wp[((qt * KKT + KRES + kk) * 64 + lane) * 8];
        }

        // ---- stage h into LDS fragment-major (64 rows x 1024 cols = 32 vec/thread) ----
        {
            const size_t gbase = (size_t)(c * 64 + srow) * HH + sseg * 256;
            const int mt_w = srow >> 4, l15w = srow & 15;
#pragma unroll
            for (int i = 0; i < 32; ++i) {          // FIX: was 16 — half of hl stayed uninit
                short8v hv = *(const short8v*)&hin[gbase + i * 8];
                const int kkh = sseg * 8 + (i >> 2);
                const int lh  = i & 3;
                *(short8v*)&hl[(size_t)((mt_w * 32 + kkh) * 64 + lh * 16 + l15w) * 8] = hv;
            }
        }
        __syncthreads();                            // S4: hl ready

        // ---- h-phase (kkh 0..31 == kk 16..47) ----
#pragma unroll
        for (int kkh = 0; kkh < 32; ++kkh) {
            short8v a0 = *(const short8v*)&hl[(size_t)(((mtp*2 + 0) * 32 + kkh) * 64 + lane) * 8];
            short8v a1 = *(const short8v*)&hl[(size_t)(((mtp*2 + 1) * 32 + kkh) * 64 + lane) * 8];
            short8v b0 = (kkh < KRES - 16) ? wres[0][16 + kkh] : wst[0][kkh - (KRES - 16)];
            short8v b1 = (kkh < KRES - 16) ? wres[1][16 + kkh] : wst[1][kkh - (KRES - 16)];
            acc[0][0] = __builtin_amdgcn_mfma_f32_16x16x32_bf16(a0, b0, acc[0][0], 0,0,0);
            acc[0][1] = __builtin_amdgcn_mfma_f32_16x16x32_bf16(a0, b1, acc[0][1], 0,0,0);
            acc[1][0] = __builtin_amdgcn_mfma_f32_16x16x32_bf16(a1, b0, acc[1][0], 0,0,0);
            acc[1][1] = __builtin_amdgcn_mfma_f32_16x16x32_bf16(a1, b1, acc[1][1], 0,0,0);
        }

        // ---- epilogue: exchange 2q halves via LDS, fused activation + state ----
#pragma unroll
        for (int ml = 0; ml < 2; ++ml)
#pragma unroll
            for (int r = 0; r < 4; ++r) {
                int row = mtp * 32 + ml * 16 + lhi * 4 + r;
                *(float2*)&gl[row * 68 + l15 * 4 + qp * 2] =
                    make_float2(acc[ml][0][r], acc[ml][1][r]);
            }
        __syncthreads();                            // S1: gates ready
        {
            float4 g0 = *(const float4*)&gl[erow * 68 + (ej0 + 0) * 4];
            float4 g1 = *(const float4*)&gl[erow * 68 + (ej0 + 1) * 4];
            float4 g2 = *(const float4*)&gl[erow * 68 + (ej0 + 2) * 4];
            float4 g3 = *(const float4*)&gl[erow * 68 + (ej0 + 3) * 4];
            ushort4 hv;
            {
                float ig = sigm(g0.x + eb[0].x), fg = sigm(g0.y + eb[0].y);
                float gg = tanh_f(g0.z + eb[0].z), og = sigm(g0.w + eb[0].w);
                ec0 = fg * ec0 + ig * gg; hv.x = f2bf(og * tanh_f(ec0));
            }
            {
                float ig = sigm(g1.x + eb[1].x), fg = sigm(g1.y + eb[1].y);
                float gg = tanh_f(g1.z + eb[1].z), og = sigm(g1.w + eb[1].w);
                ec1 = fg * ec1 + ig * gg; hv.y = f2bf(og * tanh_f(ec1));
            }
            {
                float ig = sigm(g2.x + eb[2].x), fg = sigm(g2.y + eb[2].y);
                float gg = tanh_f(g2.z + eb[2].z), og = sigm(g2.w + eb[2].w);
                ec2 = fg * ec2 + ig * gg; hv.z = f2bf(og * tanh_f(ec2));
            }
            {
                float ig = sigm(g3.x + eb[3].x), fg = sigm(g3.y + eb[3].y);
                float gg = tanh_f(g3.z + eb[3].z), og = sigm(g3.w + eb[3].w);
                ec3 = fg * ec3 + ig * gg; hv.w = f2bf(og * tanh_f(ec3));
            }
            *(ushort4*)&hout[(size_t)(c * 64 + erow) * HH + jg * 16 + ej0] = hv;
        }
    }
}

// ---------------------------------------------------------------------------
// out[128,1024] = h_fin @ fc_w^T + fc_b  (fp32). 32 WGs: 2 Mg x 16 Ng.
// ---------------------------------------------------------------------------
__launch_bounds__(256)
__global__ void fc_kernel(const unsigned short* __restrict__ hfin,
                          const unsigned short* __restrict__ wfc,
                          const float* __restrict__ fc_b,
                          float* __restrict__ out) {
    __shared__ __align__(16) char smem[64 * USTRIDE * 2];
    unsigned short* ulds = (unsigned short*)smem;
    const int tid = threadIdx.x, bid = blockIdx.x;
    const int mg = bid >> 4;
    const int ng = bid & 15;
    const int m0 = mg * 64;
    const int lane = tid & 63, wave = tid >> 6;
    const int wm = wave >> 1, wn = wave & 1;

    float4v acc[2][2] = {};
    for (int cc = 0; cc < 4; ++cc) {
        __syncthreads();
        for (int it = 0; it < 16; ++it) {
            int v = tid + 256 * it;
            int row = v >> 6;
            int kl = (v & 63) * 4;
            ushort4 hv = *(const ushort4*)&hfin[(size_t)(m0 + row) * HH + cc * 256 + kl];
            *(ushort4*)&ulds[row * USTRIDE + kl] = hv;
        }
        __syncthreads();
#pragma unroll
        for (int kk = 0; kk < 8; ++kk) {
            int kkg = cc * 8 + kk;
            short8v a[2], b[2];
#pragma unroll
            for (int mt = 0; mt < 2; ++mt) {
                int row = wm * 32 + mt * 16 + (lane & 15);
                a[mt] = *(const short8v*)&ulds[row * USTRIDE + kk * 32 + (lane >> 4) * 8];
            }
#pragma unroll
            for (int nt = 0; nt < 2; ++nt) {
                int ntile = ng * 4 + wn * 2 + nt;
                b[nt] = *(const short8v*)&wfc[(((size_t)ntile * KK_FC + kkg) * 64 + lane) * 8];
            }
#pragma unroll
            for (int mt = 0; mt < 2; ++mt)
#pragma unroll
                for (int nt = 0; nt < 2; ++nt)
                    acc[mt][nt] = __builtin_amdgcn_mfma_f32_16x16x32_bf16(
                        a[mt], b[nt], acc[mt][nt], 0, 0, 0);
        }
    }
#pragma unroll
    for (int mt = 0; mt < 2; ++mt)
#pragma unroll
        for (int nt = 0; nt < 2; ++nt)
#pragma unroll
            for (int r = 0; r < 4; ++r) {
                int mrow = m0 + wm * 32 + mt * 16 + (lane >> 4) * 4 + r;
                int o = ng * 64 + wn * 32 + nt * 16 + (lane & 15);
                out[(size_t)mrow * HH + o] = acc[mt][nt][r] + fc_b[o];
            }
}

// ---------------------------------------------------------------------------
extern "C" void kernel_launch(void* const* d_in, const int* in_sizes, int n_in,
                              void* d_out, int out_size, void* d_ws, size_t ws_size,
                              hipStream_t stream) {
    const float* x    = (const float*)d_in[0];
    const float* W_ih = (const float*)d_in[1];
    const float* W_hh = (const float*)d_in[2];
    const float* b_ih = (const float*)d_in[3];
    const float* b_hh = (const float*)d_in[4];
    const float* fc_w = (const float*)d_in[5];
    const float* fc_b = (const float*)d_in[6];
    float* out = (float*)d_out;

    char* ws = (char*)d_ws;
    size_t off = 0;
    unsigned short* wp  = (unsigned short*)(ws + off); off += (size_t)256 * KKT * 64 * 8 * 2;  // 12 MB
    unsigned short* wfc = (unsigned short*)(ws + off); off += (size_t)NT_FC * KK_FC * 64 * 8 * 2; // 2 MB
    float* bp  = (float*)(ws + off); off += (size_t)G4 * 4;
    unsigned short* hbuf0 = (unsigned short*)(ws + off); off += (size_t)BB * HH * 2;
    unsigned short* hbuf1 = (unsigned short*)(ws + off); off += (size_t)BB * HH * 2;
    unsigned int* bar = (unsigned int*)(ws + off); off += 2048 * 4;
    size_t off_min = off;
    unsigned short* xpre = (unsigned short*)(ws + off);
    size_t off_full = off + (size_t)8 * SS * 16 * 64 * 8 * 2;                                  // +67 MB
    if (ws_size < off_min) return;
    const bool pre = (ws_size >= off_full);

    pack_w_kernel<<<3072, 256, 0, stream>>>(W_ih, W_hh, wp);
    pack_fc_kernel<<<512, 256, 0, stream>>>(fc_w, wfc);
    init_kernel<<<512, 256, 0, stream>>>(b_ih, b_hh, hbuf0, bp, bar);
    if (pre) {
        pack_x_kernel<<<16384, 256, 0, stream>>>(x, xpre);
        lstm_persist<1><<<128, 256, 0, stream>>>(x, xpre, wp, bp, hbuf0, hbuf1, bar);
    } else {
        lstm_persist<0><<<128, 256, 0, stream>>>(x, xpre, wp, bp, hbuf0, hbuf1, bar);
    }

    // S=512 even -> final h in hbuf0
    fc_kernel<<<32, 256, 0, stream>>>(hbuf0, wfc, fc_b, out);
}

// Round 5
// 4105.666 us; speedup vs baseline: 3.0328x; 3.0106x over previous
//
#include <hip/hip_runtime.h>
#include <stdint.h>

// Problem constants
#define BB   128
#define DD   512
#define HH   1024
#define SS   512
#define G4   4096
#define KKT  48       // (D+H)/32 k-steps: kk 0..15 = x, 16..47 = h
#define NT_FC 64
#define KK_FC 32
#define USTRIDE 264   // fc kernel LDS stride

typedef __attribute__((ext_vector_type(8))) short short8v;
typedef __attribute__((ext_vector_type(4))) float float4v;
typedef __attribute__((ext_vector_type(4))) unsigned int uint4v;

__device__ __forceinline__ unsigned short f2bf(float f) {
    union { float f; unsigned int u; } v; v.f = f;
    unsigned int u = v.u;
    unsigned int r = u + 0x7FFFu + ((u >> 16) & 1u);   // RNE
    return (unsigned short)(r >> 16);
}
__device__ __forceinline__ float sigm(float z) { return 1.f / (1.f + __expf(-z)); }
__device__ __forceinline__ float tanh_f(float z) { float e = __expf(2.f * z); return 1.f - 2.f / (e + 1.f); }

__device__ __forceinline__ short8v cvt8(const float4 f0, const float4 f1) {
    short8v o;
    o[0]=(short)f2bf(f0.x); o[1]=(short)f2bf(f0.y); o[2]=(short)f2bf(f0.z); o[3]=(short)f2bf(f0.w);
    o[4]=(short)f2bf(f1.x); o[5]=(short)f2bf(f1.y); o[6]=(short)f2bf(f1.z); o[7]=(short)f2bf(f1.w);
    return o;
}

// ---------------------------------------------------------------------------
// Pack W = [W_ih | W_hh] into bf16 MFMA fragment order, q-major n-tiles:
// ntile = q*64 + jg  ->  W row = q*H + jg*16 + (lane&15), k = kk*32+(lane>>4)*8
// ---------------------------------------------------------------------------
__global__ void pack_w_kernel(const float* __restrict__ W_ih,
                              const float* __restrict__ W_hh,
                              unsigned short* __restrict__ wp) {
    int idx = blockIdx.x * 256 + threadIdx.x;
    if (idx >= 256 * KKT * 64) return;
    int lane  = idx & 63;
    int kk    = (idx >> 6) % KKT;
    int ntile = idx / (64 * KKT);
    int q = ntile >> 6;
    int orow = q * HH + (ntile & 63) * 16 + (lane & 15);
    int kbase = kk * 32 + (lane >> 4) * 8;
    short8v ov;
#pragma unroll
    for (int i = 0; i < 8; ++i) {
        int k = kbase + i;
        float v = (k < DD) ? W_ih[(size_t)orow * DD + k]
                           : W_hh[(size_t)orow * HH + (k - DD)];
        ov[i] = (short)f2bf(v);
    }
    *(short8v*)&wp[(size_t)idx * 8] = ov;
}

__global__ void pack_fc_kernel(const float* __restrict__ fc_w,
                               unsigned short* __restrict__ wfc) {
    int idx = blockIdx.x * 256 + threadIdx.x;
    if (idx >= NT_FC * KK_FC * 64) return;
    int lane  = idx & 63;
    int kk    = (idx >> 6) % KK_FC;
    int ntile = idx / (64 * KK_FC);
    int o = ntile * 16 + (lane & 15);
    int kbase = kk * 32 + (lane >> 4) * 8;
    short8v ov;
#pragma unroll
    for (int i = 0; i < 8; ++i)
        ov[i] = (short)f2bf(fc_w[(size_t)o * HH + kbase + i]);
    *(short8v*)&wfc[(size_t)idx * 8] = ov;
}

// x -> bf16 MFMA A-fragment order: xpre[((mtile*S + t)*16 + kk)*64 + lane]
__global__ void pack_x_kernel(const float* __restrict__ x,
                              unsigned short* __restrict__ xpre) {
    int idx = blockIdx.x * 256 + threadIdx.x;
    if (idx >= 8 * SS * 16 * 64) return;
    int lane  = idx & 63;
    int kk    = (idx >> 6) & 15;
    int t     = (idx >> 10) & (SS - 1);
    int mtile = idx >> 19;
    int b = mtile * 16 + (lane & 15);
    int d = kk * 32 + (lane >> 4) * 8;
    const float* src = &x[((size_t)b * SS + t) * DD + d];
    short8v ov;
#pragma unroll
    for (int i = 0; i < 8; ++i) ov[i] = (short)f2bf(src[i]);
    *(short8v*)&xpre[(size_t)idx * 8] = ov;
}

// zero h0 + barrier slots, pack bias bp[j*4+q] = b_ih[q*H+j] + b_hh[q*H+j]
__global__ void init_kernel(const float* __restrict__ b_ih,
                            const float* __restrict__ b_hh,
                            unsigned short* __restrict__ h0,
                            float* __restrict__ bpp,
                            unsigned int* __restrict__ bar) {
    int i = blockIdx.x * 256 + threadIdx.x;
    if (i < BB * HH) h0[i] = 0;
    if (i < G4) { int j = i >> 2, q = i & 3; bpp[i] = b_ih[q * HH + j] + b_hh[q * HH + j]; }
    if (i < 4096) bar[i] = 0;
}

// ---------------------------------------------------------------------------
// Persistent LSTM: 256 WGs = 4 chains (32 batch rows) x 64 WGs (16 j-units).
// Wave (mt, qp): 1 m-tile x 2 q-tiles x 48 kk = 96 MFMAs/step.
// W: kk 0..25 VGPR-resident, kk 26..47 in LDS (loaded once). No atomics, no
// fences: h + barrier slots move via sc0/sc1 (MALL-coherent) asm ops, so L2
// stays warm for W/x the whole kernel.
// ---------------------------------------------------------------------------
template<int PRE>
__launch_bounds__(256, 1)
__global__ void lstm_persist(const float* __restrict__ x,
                             const unsigned short* __restrict__ xpre,
                             const unsigned short* __restrict__ wp,
                             const float* __restrict__ bp,
                             unsigned short* __restrict__ hbuf0,
                             unsigned short* __restrict__ hbuf1,
                             unsigned int* __restrict__ bar) {
    __shared__ __align__(16) unsigned short wlds[4 * 22 * 64 * 8];  // 88 KiB W kk26..47
    __shared__ __align__(16) unsigned short hl[2 * 32 * 64 * 8];    // 64 KiB h frags (swizzled)
    float* gl = (float*)hl;                                         // gate exchange alias (8.7 KiB)

    const int tid  = threadIdx.x;
    const int bid  = blockIdx.x;
    const int chain = bid >> 6;                 // 0..3
    const int jg    = bid & 63;                 // 0..63  (XCD = jg%8 for all chains)
    const int lane = tid & 63;
    const int w    = tid >> 6;
    const int mt   = w >> 1;                    // m-tile 0..1
    const int qp   = w & 1;                     // q pair 0..1
    const int l15  = lane & 15;
    const int lhi  = lane >> 4;

    // ---- resident W kk 0..15 (x) and 16..25 (h) ----
    short8v wx[2][16], wh[2][10];
#pragma unroll
    for (int qi = 0; qi < 2; ++qi) {
        const size_t qt = (size_t)((qp * 2 + qi) * 64 + jg);
#pragma unroll
        for (int kk = 0; kk < 16; ++kk)
            wx[qi][kk] = *(const short8v*)&wp[((qt * KKT + kk) * 64 + lane) * 8];
#pragma unroll
        for (int kk = 0; kk < 10; ++kk)
            wh[qi][kk] = *(const short8v*)&wp[((qt * KKT + 16 + kk) * 64 + lane) * 8];
    }
    // ---- LDS W kk 26..47 (4 q-tiles x 22 kk), loaded once ----
#pragma unroll
    for (int i = 0; i < 22; ++i) {
        int f  = tid + 256 * i;                 // 0..5631
        int sl = f & 63, rest = f >> 6;
        int kx = rest % 22, qt = rest / 22;
        *(short8v*)&wlds[(size_t)f * 8] =
            *(const short8v*)&wp[(((size_t)(qt * 64 + jg) * KKT + 26 + kx) * 64 + sl) * 8];
    }

    // ---- epilogue constants: thread owns rows erow, units ejp, ejp+1 ----
    const int erow = tid >> 3;                  // 0..31
    const int ejp  = (tid & 7) * 2;             // 0..14
    const float4 eb0 = *(const float4*)&bp[(jg * 16 + ejp) * 4];
    const float4 eb1 = *(const float4*)&bp[(jg * 16 + ejp + 1) * 4];
    float ec0 = 0.f, ec1 = 0.f;

    __syncthreads();                            // wlds ready

#pragma unroll 1
    for (int t = 0; t < SS; ++t) {
        const unsigned short* hin = (t & 1) ? hbuf1 : hbuf0;
        unsigned short* hout      = (t & 1) ? hbuf0 : hbuf1;

        __syncthreads();                        // S2: prev-iter h stores drained by all

        // ---- arrive: publish "my h(t-1) is visible" ----
        if (t > 0 && tid == 0) {
            const unsigned int* sp = bar + chain * 64 + jg;
            unsigned int tv = (unsigned int)t;
            asm volatile("global_store_dword %0, %1, off sc0 sc1"
                         :: "v"(sp), "v"(tv) : "memory");
        }

        float4v acc0 = {0.f, 0.f, 0.f, 0.f};
        float4v acc1 = {0.f, 0.f, 0.f, 0.f};

        // ---- x-phase (kk 0..15) — no h dependence, overlaps barrier ----
#pragma unroll
        for (int kk = 0; kk < 16; ++kk) {
            short8v a;
            if (PRE) {
                a = *(const short8v*)&xpre[(((size_t)((chain * 2 + mt) * SS + t) * 16 + kk) * 64 + lane) * 8];
            } else {
                const float* p = &x[((size_t)(chain * 32 + mt * 16 + l15) * SS + t) * DD + kk * 32 + lhi * 8];
                a = cvt8(*(const float4*)p, *(const float4*)(p + 4));
            }
            acc0 = __builtin_amdgcn_mfma_f32_16x16x32_bf16(a, wx[0][kk], acc0, 0, 0, 0);
            acc1 = __builtin_amdgcn_mfma_f32_16x16x32_bf16(a, wx[1][kk], acc1, 0, 0, 0);
        }

        // ---- barrier wait: wave 0 polls the chain's 64 slots ----
        if (t > 0 && w == 0) {
            const unsigned int* sp = bar + chain * 64 + lane;
            unsigned int v;
            for (;;) {
                asm volatile("global_load_dword %0, %1, off sc0 sc1\n\ts_waitcnt vmcnt(0)"
                             : "=v"(v) : "v"(sp) : "memory");
                if (!__any(v < (unsigned int)t)) break;
                __builtin_amdgcn_s_sleep(2);
            }
        }
        __syncthreads();                        // S3: h(t-1) globally visible

        // ---- stage h(t-1): 16 sc1 16B loads/thread -> swizzled hl ----
        {
            const char* hbase = (const char*)hin + ((size_t)chain * 32 * HH) * 2 + (size_t)tid * 16;
            uint4v r0,r1,r2,r3,r4,r5,r6,r7,r8,r9,r10,r11,r12,r13,r14,r15;
#define HLD(R, I) asm volatile("global_load_dwordx4 %0, %1, off sc0 sc1" \
                               : "=v"(R) : "v"(hbase + (I) * 4096) : "memory")
            HLD(r0,0); HLD(r1,1); HLD(r2,2); HLD(r3,3); HLD(r4,4); HLD(r5,5); HLD(r6,6); HLD(r7,7);
            HLD(r8,8); HLD(r9,9); HLD(r10,10); HLD(r11,11); HLD(r12,12); HLD(r13,13); HLD(r14,14); HLD(r15,15);
#undef HLD
            asm volatile("s_waitcnt vmcnt(0)" ::: "memory");
            __builtin_amdgcn_sched_barrier(0);
#define HST(R, I) { int v_ = tid + 256 * (I); int row_ = v_ >> 7, c8_ = v_ & 127;            \
        int byte_ = (((((row_ >> 4) * 32 + (c8_ >> 2)) * 64 + (c8_ & 3) * 16 + (row_ & 15)) * 16) \
                     ^ (((c8_ >> 2) & 7) << 4));                                              \
        *(uint4v*)((char*)hl + byte_) = R; }
            HST(r0,0); HST(r1,1); HST(r2,2); HST(r3,3); HST(r4,4); HST(r5,5); HST(r6,6); HST(r7,7);
            HST(r8,8); HST(r9,9); HST(r10,10); HST(r11,11); HST(r12,12); HST(r13,13); HST(r14,14); HST(r15,15);
#undef HST
        }
        __syncthreads();                        // S4: hl ready

        // ---- h-phase (kkh 0..31 == kk 16..47) ----
#pragma unroll
        for (int kkh = 0; kkh < 32; ++kkh) {
            int abyte = (((mt * 32 + kkh) * 64 + lane) * 16) ^ ((kkh & 7) << 4);
            short8v a = *(const short8v*)((char*)hl + abyte);
            short8v b0, b1;
            if (kkh < 10) { b0 = wh[0][kkh]; b1 = wh[1][kkh]; }
            else {
                b0 = *(const short8v*)&wlds[(size_t)(((qp * 2 + 0) * 22 + kkh - 10) * 64 + lane) * 8];
                b1 = *(const short8v*)&wlds[(size_t)(((qp * 2 + 1) * 22 + kkh - 10) * 64 + lane) * 8];
            }
            acc0 = __builtin_amdgcn_mfma_f32_16x16x32_bf16(a, b0, acc0, 0, 0, 0);
            acc1 = __builtin_amdgcn_mfma_f32_16x16x32_bf16(a, b1, acc1, 0, 0, 0);
        }
        __syncthreads();                        // S5: hl dead -> gl alias safe

        // ---- gate exchange ----
#pragma unroll
        for (int r = 0; r < 4; ++r) {
            int row = mt * 16 + lhi * 4 + r;
            *(float2*)&gl[row * 68 + l15 * 4 + qp * 2] = make_float2(acc0[r], acc1[r]);
        }
        __syncthreads();                        // S1: gates ready

        // ---- fused activation + state, h store (sc1, self-drained) ----
        {
            float4 g0 = *(const float4*)&gl[erow * 68 + (ejp + 0) * 4];
            float4 g1 = *(const float4*)&gl[erow * 68 + (ejp + 1) * 4];
            float h0v, h1v;
            {
                float ig = sigm(g0.x + eb0.x), fg = sigm(g0.y + eb0.y);
                float gg = tanh_f(g0.z + eb0.z), og = sigm(g0.w + eb0.w);
                ec0 = fg * ec0 + ig * gg; h0v = og * tanh_f(ec0);
            }
            {
                float ig = sigm(g1.x + eb1.x), fg = sigm(g1.y + eb1.y);
                float gg = tanh_f(g1.z + eb1.z), og = sigm(g1.w + eb1.w);
                ec1 = fg * ec1 + ig * gg; h1v = og * tanh_f(ec1);
            }
            unsigned int hv = (unsigned int)f2bf(h0v) | ((unsigned int)f2bf(h1v) << 16);
            const unsigned short* hp = &hout[(size_t)(chain * 32 + erow) * HH + jg * 16 + ejp];
            asm volatile("global_store_dword %0, %1, off sc0 sc1\n\ts_waitcnt vmcnt(0)"
                         :: "v"(hp), "v"(hv) : "memory");
        }
    }
}

// ---------------------------------------------------------------------------
// out[128,1024] = h_fin @ fc_w^T + fc_b  (fp32). 32 WGs: 2 Mg x 16 Ng.
// ---------------------------------------------------------------------------
__launch_bounds__(256)
__global__ void fc_kernel(const unsigned short* __restrict__ hfin,
                          const unsigned short* __restrict__ wfc,
                          const float* __restrict__ fc_b,
                          float* __restrict__ out) {
    __shared__ __align__(16) char smem[64 * USTRIDE * 2];
    unsigned short* ulds = (unsigned short*)smem;
    const int tid = threadIdx.x, bid = blockIdx.x;
    const int mg = bid >> 4;
    const int ng = bid & 15;
    const int m0 = mg * 64;
    const int lane = tid & 63, wave = tid >> 6;
    const int wm = wave >> 1, wn = wave & 1;

    float4v acc[2][2] = {};
    for (int cc = 0; cc < 4; ++cc) {
        __syncthreads();
        for (int it = 0; it < 16; ++it) {
            int v = tid + 256 * it;
            int row = v >> 6;
            int kl = (v & 63) * 4;
            ushort4 hv = *(const ushort4*)&hfin[(size_t)(m0 + row) * HH + cc * 256 + kl];
            *(ushort4*)&ulds[row * USTRIDE + kl] = hv;
        }
        __syncthreads();
#pragma unroll
        for (int kk = 0; kk < 8; ++kk) {
            int kkg = cc * 8 + kk;
            short8v a[2], b[2];
#pragma unroll
            for (int mtl = 0; mtl < 2; ++mtl) {
                int row = wm * 32 + mtl * 16 + (lane & 15);
                a[mtl] = *(const short8v*)&ulds[row * USTRIDE + kk * 32 + (lane >> 4) * 8];
            }
#pragma unroll
            for (int nt = 0; nt < 2; ++nt) {
                int ntile = ng * 4 + wn * 2 + nt;
                b[nt] = *(const short8v*)&wfc[(((size_t)ntile * KK_FC + kkg) * 64 + lane) * 8];
            }
#pragma unroll
            for (int mtl = 0; mtl < 2; ++mtl)
#pragma unroll
                for (int nt = 0; nt < 2; ++nt)
                    acc[mtl][nt] = __builtin_amdgcn_mfma_f32_16x16x32_bf16(
                        a[mtl], b[nt], acc[mtl][nt], 0, 0, 0);
        }
    }
#pragma unroll
    for (int mtl = 0; mtl < 2; ++mtl)
#pragma unroll
        for (int nt = 0; nt < 2; ++nt)
#pragma unroll
            for (int r = 0; r < 4; ++r) {
                int mrow = m0 + wm * 32 + mtl * 16 + (lane >> 4) * 4 + r;
                int o = ng * 64 + wn * 32 + nt * 16 + (lane & 15);
                out[(size_t)mrow * HH + o] = acc[mtl][nt][r] + fc_b[o];
            }
}

// ---------------------------------------------------------------------------
extern "C" void kernel_launch(void* const* d_in, const int* in_sizes, int n_in,
                              void* d_out, int out_size, void* d_ws, size_t ws_size,
                              hipStream_t stream) {
    const float* x    = (const float*)d_in[0];
    const float* W_ih = (const float*)d_in[1];
    const float* W_hh = (const float*)d_in[2];
    const float* b_ih = (const float*)d_in[3];
    const float* b_hh = (const float*)d_in[4];
    const float* fc_w = (const float*)d_in[5];
    const float* fc_b = (const float*)d_in[6];
    float* out = (float*)d_out;

    char* ws = (char*)d_ws;
    size_t off = 0;
    unsigned short* wp  = (unsigned short*)(ws + off); off += (size_t)256 * KKT * 64 * 8 * 2;     // 12 MB
    unsigned short* wfc = (unsigned short*)(ws + off); off += (size_t)NT_FC * KK_FC * 64 * 8 * 2; // 2 MB
    float* bp  = (float*)(ws + off); off += (size_t)G4 * 4;
    unsigned short* hbuf0 = (unsigned short*)(ws + off); off += (size_t)BB * HH * 2;
    unsigned short* hbuf1 = (unsigned short*)(ws + off); off += (size_t)BB * HH * 2;
    unsigned int* bar = (unsigned int*)(ws + off); off += 4096 * 4;
    size_t off_min = off;
    unsigned short* xpre = (unsigned short*)(ws + off);
    size_t off_full = off + (size_t)8 * SS * 16 * 64 * 8 * 2;                                     // +67 MB
    if (ws_size < off_min) return;
    const bool pre = (ws_size >= off_full);

    pack_w_kernel<<<3072, 256, 0, stream>>>(W_ih, W_hh, wp);
    pack_fc_kernel<<<512, 256, 0, stream>>>(fc_w, wfc);
    init_kernel<<<512, 256, 0, stream>>>(b_ih, b_hh, hbuf0, bp, bar);
    if (pre) {
        pack_x_kernel<<<16384, 256, 0, stream>>>(x, xpre);
        lstm_persist<1><<<256, 256, 0, stream>>>(x, xpre, wp, bp, hbuf0, hbuf1, bar);
    } else {
        lstm_persist<0><<<256, 256, 0, stream>>>(x, xpre, wp, bp, hbuf0, hbuf1, bar);
    }

    // S=512 even -> final h in hbuf0
    fc_kernel<<<32, 256, 0, stream>>>(hbuf0, wfc, fc_b, out);
}